// Round 1
// baseline (221.188 us; speedup 1.0000x reference)
//
#include <hip/hip_runtime.h>
#include <math.h>

#define BB 2
#define CC 45
#define HH 160
#define WW 160
#define VV 724
#define HWW (HH*WW)
#define NPIX (BB*HWW)      // 51200
#define PIX 8
#define NBLK (NPIX/PIX)    // 6400
#define TPB 256
#define CEPS 1e-3f
#define CEPS2 (CEPS*CEPS)
#define NQ 9
#define WSSTRIDE 16

__device__ __forceinline__ float charb_(float x){ return sqrtf(fmaf(x,x,CEPS2)); }

__device__ __forceinline__ float red64_(float v){
  #pragma unroll
  for (int off=32; off; off>>=1) v += __shfl_xor(v, off, 64);
  return v;
}
__device__ __forceinline__ float red32_(float v){
  #pragma unroll
  for (int off=16; off; off>>=1) v += __shfl_xor(v, off, 32);
  return v;
}

__device__ __forceinline__ void top5_ins(float x, int ix, float v[5], int id[5]){
  if (x > v[4]) {
    v[4]=x; id[4]=ix;
    #pragma unroll
    for (int j=4; j>0; --j){
      if (v[j] > v[j-1]) {
        float tv=v[j]; v[j]=v[j-1]; v[j-1]=tv;
        int tq=id[j]; id[j]=id[j-1]; id[j-1]=tq;
      }
    }
  }
}

__global__ __launch_bounds__(TPB, 3)
void fodf_main(const float* __restrict__ pred, const float* __restrict__ tgt,
               const float* __restrict__ sf, const float* __restrict__ mask,
               float* __restrict__ ws)
{
  __shared__ __align__(16) float sPred[CC][PIX];
  __shared__ __align__(16) float sTgt[CC][PIX];
  __shared__ float sfP[PIX][VV];
  __shared__ float sfT[PIX][VV];
  __shared__ float sTopV[PIX][5];
  __shared__ int   sTopI[PIX][5];
  __shared__ float sMask[PIX];
  __shared__ float sRed[4][NQ];

  const int tid = threadIdx.x;
  const int pix0 = blockIdx.x * PIX;

  // ---- load channels into LDS ----
  for (int i = tid; i < CC*PIX; i += TPB) {
    int c = i / PIX, p = i - c*PIX;
    int pid = pix0 + p;
    int b = pid / HWW, hw = pid - b*HWW;
    size_t off = (size_t)(b*CC + c)*HWW + hw;
    sPred[c][p] = pred[off];
    sTgt[c][p]  = tgt[off];
  }
  if (tid < PIX) sMask[tid] = mask[pix0 + tid];
  __syncthreads();

  // ---- phase 1: dual matvec (pred_sf, target_sf) into LDS ----
  {
    const int v0 = tid, v1 = tid + TPB, v2 = tid + 2*TPB;
    const bool a2 = (v2 < VV);
    const int v2c = a2 ? v2 : v0;
    float aP0[PIX]={}, aP1[PIX]={}, aP2[PIX]={};
    float aT0[PIX]={}, aT1[PIX]={}, aT2[PIX]={};
    const float4* p4 = reinterpret_cast<const float4*>(&sPred[0][0]);
    const float4* t4 = reinterpret_cast<const float4*>(&sTgt[0][0]);
    const float* sfr = sf;
    for (int c = 0; c < CC; ++c) {
      float pc[8], tc[8];
      *reinterpret_cast<float4*>(&pc[0]) = p4[2*c];
      *reinterpret_cast<float4*>(&pc[4]) = p4[2*c+1];
      *reinterpret_cast<float4*>(&tc[0]) = t4[2*c];
      *reinterpret_cast<float4*>(&tc[4]) = t4[2*c+1];
      float s0 = sfr[v0];
      float s1 = sfr[v1];
      float s2 = sfr[v2c];
      if (!a2) s2 = 0.f;
      #pragma unroll
      for (int p=0;p<PIX;++p){
        aP0[p] = fmaf(s0, pc[p], aP0[p]);
        aT0[p] = fmaf(s0, tc[p], aT0[p]);
        aP1[p] = fmaf(s1, pc[p], aP1[p]);
        aT1[p] = fmaf(s1, tc[p], aT1[p]);
        aP2[p] = fmaf(s2, pc[p], aP2[p]);
        aT2[p] = fmaf(s2, tc[p], aT2[p]);
      }
      sfr += VV;
    }
    #pragma unroll
    for (int p=0;p<PIX;++p){
      sfP[p][v0]=aP0[p]; sfT[p][v0]=aT0[p];
      sfP[p][v1]=aP1[p]; sfT[p][v1]=aT1[p];
      if (a2){ sfP[p][v2]=aP2[p]; sfT[p][v2]=aT2[p]; }
    }
  }

  // ---- phase 2: per-pixel channel stats (fodf, corr, power) ----
  float q_fodf=0, q_corr=0, q_power=0, q_mask=0;
  {
    int g = tid >> 5, lane = tid & 31;
    int p = g;
    float mp = sMask[p];
    float sp=0,st=0,spp=0,stt=0,spt=0,fod=0;
    float bp0=0,bp1=0,bp2=0,bp3=0,bp4=0;
    float bt0=0,bt1=0,bt2=0,bt3=0,bt4=0;
    #pragma unroll
    for (int cc2=0; cc2<2; ++cc2){
      int c = lane + 32*cc2;
      if (c < CC) {
        float pv = sPred[c][p], tv = sTgt[c][p];
        float p2 = pv*pv, t2 = tv*tv;
        sp+=pv; st+=tv; spp+=p2; stt+=t2; spt+=pv*tv;
        float d = pv-tv; fod += charb_(d);
        bp0 += (c<1)?p2:0.f;           bt0 += (c<1)?t2:0.f;
        bp1 += (c>=1&&c<6)?p2:0.f;     bt1 += (c>=1&&c<6)?t2:0.f;
        bp2 += (c>=6&&c<15)?p2:0.f;    bt2 += (c>=6&&c<15)?t2:0.f;
        bp3 += (c>=15&&c<28)?p2:0.f;   bt3 += (c>=15&&c<28)?t2:0.f;
        bp4 += (c>=28)?p2:0.f;         bt4 += (c>=28)?t2:0.f;
      }
    }
    sp=red32_(sp); st=red32_(st); spp=red32_(spp); stt=red32_(stt); spt=red32_(spt);
    fod=red32_(fod);
    bp0=red32_(bp0); bp1=red32_(bp1); bp2=red32_(bp2); bp3=red32_(bp3); bp4=red32_(bp4);
    bt0=red32_(bt0); bt1=red32_(bt1); bt2=red32_(bt2); bt3=red32_(bt3); bt4=red32_(bt4);
    if (lane == 0) {
      const float n = (float)CC;
      float mpm = sp/n, mtm = st/n;
      float cov = spt - n*mpm*mtm;
      float vp = spp - n*mpm*mpm;
      float vt = stt - n*mtm*mtm;
      float denom = sqrtf(fmaxf(vp,0.f))*sqrtf(fmaxf(vt,0.f)) + 1e-6f;
      float corr = cov/denom;
      q_corr = (1.f - corr)*mp;
      q_fodf = fod*mp;
      float pw = 0.f;
      pw += charb_(sqrtf(bp0+CEPS2) - sqrtf(bt0+CEPS2));
      pw += charb_(sqrtf(bp1+CEPS2) - sqrtf(bt1+CEPS2));
      pw += charb_(sqrtf(bp2+CEPS2) - sqrtf(bt2+CEPS2));
      pw += charb_(sqrtf(bp3+CEPS2) - sqrtf(bt3+CEPS2));
      pw += charb_(sqrtf(bp4+CEPS2) - sqrtf(bt4+CEPS2));
      q_power = pw*mp;
      q_mask = mp;
    }
  }
  __syncthreads();

  // ---- phase 3: top-5 of relu(target_sf) per pixel (32 lanes / pixel) ----
  {
    int g = tid >> 5, lane = tid & 31;
    int p = g;
    float tv_[5]={-1.f,-1.f,-1.f,-1.f,-1.f};
    int   ti_[5]={0,0,0,0,0};
    for (int v = lane; v < VV; v += 32) {
      float x = fmaxf(sfT[p][v], 0.f);
      top5_ins(x, v, tv_, ti_);
    }
    #pragma unroll
    for (int off=16; off; off>>=1) {
      float ov[5]; int oi[5];
      #pragma unroll
      for (int j=0;j<5;++j){ ov[j]=__shfl_xor(tv_[j],off,32); oi[j]=__shfl_xor(ti_[j],off,32); }
      #pragma unroll
      for (int j=0;j<5;++j) top5_ins(ov[j], oi[j], tv_, ti_);
    }
    if (lane == 0) {
      #pragma unroll
      for (int j=0;j<5;++j){ sTopV[p][j]=tv_[j]; sTopI[p][j]=ti_[j]; }
    }
  }
  __syncthreads();

  // ---- phase 4: sf_loss / nonneg / peak ----
  float q_sfn=0, q_sfd=0, q_nn=0, q_pk=0, q_cnt=0;
  #pragma unroll 1
  for (int p=0;p<PIX;++p){
    float mp = sMask[p];
    float invp = 1.f / fmaxf(sTopV[p][0], 1e-6f);
    for (int v = tid; v < VV; v += TPB) {
      float ts = sfT[p][v], ps = sfP[p][v];
      float pos = fmaxf(ts, 0.f);
      float tn = pos*invp;
      float wgt = fmaf(4.f*tn, tn, 1.f)*mp;
      float r = ps - ts;
      q_sfn += charb_(r)*wgt;
      q_sfd += wgt;
      q_nn  += fmaxf(-ps, 0.f)*mp;
    }
  }
  if (tid < PIX*5) {
    int p = tid/5, k = tid - 5*(tid/5);
    float tv = sTopV[p][k];
    float thr = 0.25f * fmaxf(sTopV[p][0], 1e-6f);
    if (tv > thr && sMask[p] > 0.5f) {
      int idx = sTopI[p][k];
      float acc = 0.f;
      #pragma unroll
      for (int c=0;c<CC;++c) acc = fmaf(sf[c*VV+idx], sPred[c][p], acc);
      q_pk = charb_(acc - tv);
      q_cnt = 1.f;
    }
  }

  // ---- block reduction -> per-block partials ----
  float q[NQ] = {q_fodf, q_corr, q_sfn, q_sfd, q_nn, q_pk, q_cnt, q_power, q_mask};
  #pragma unroll
  for (int i=0;i<NQ;++i) q[i] = red64_(q[i]);
  if ((tid & 63) == 0) {
    #pragma unroll
    for (int i=0;i<NQ;++i) sRed[tid>>6][i] = q[i];
  }
  __syncthreads();
  if (tid < NQ) {
    float s = sRed[0][tid]+sRed[1][tid]+sRed[2][tid]+sRed[3][tid];
    ws[blockIdx.x*WSSTRIDE + tid] = s;
  }
}

__global__ __launch_bounds__(TPB)
void fodf_final(const float* __restrict__ ws, float* __restrict__ out)
{
  const int tid = threadIdx.x;
  float s[NQ];
  #pragma unroll
  for (int i=0;i<NQ;++i) s[i]=0.f;
  for (int i = tid; i < NBLK; i += TPB) {
    #pragma unroll
    for (int qq=0;qq<NQ;++qq) s[qq] += ws[i*WSSTRIDE+qq];
  }
  #pragma unroll
  for (int i=0;i<NQ;++i) s[i] = red64_(s[i]);
  __shared__ float sw[4][NQ];
  if ((tid&63)==0){
    #pragma unroll
    for (int i=0;i<NQ;++i) sw[tid>>6][i]=s[i];
  }
  __syncthreads();
  if (tid==0){
    float t[NQ];
    #pragma unroll
    for (int i=0;i<NQ;++i) t[i]=sw[0][i]+sw[1][i]+sw[2][i]+sw[3][i];
    float msum = t[8];
    float fodf_loss = t[0]/fmaxf(msum*45.f,1.f);
    float corr_loss = t[1]/fmaxf(msum,1.f);
    float sf_loss   = t[2]/fmaxf(t[3],1.f);
    float nonneg    = t[4]/fmaxf(msum*724.f,1.f);
    float peak      = t[5]/fmaxf(t[6],1.f);
    float power     = t[7]/fmaxf(msum*5.f,1.f);
    out[0] = fodf_loss + 0.1f*corr_loss + sf_loss + 0.5f*peak + 0.1f*nonneg + 0.1f*power;
  }
}

extern "C" void kernel_launch(void* const* d_in, const int* in_sizes, int n_in,
                              void* d_out, int out_size, void* d_ws, size_t ws_size,
                              hipStream_t stream) {
  const float* pred = (const float*)d_in[0];
  const float* tgt  = (const float*)d_in[1];
  const float* sf   = (const float*)d_in[2];
  const float* mask = (const float*)d_in[3];
  float* ws  = (float*)d_ws;
  float* out = (float*)d_out;
  fodf_main<<<NBLK, TPB, 0, stream>>>(pred, tgt, sf, mask, ws);
  fodf_final<<<1, TPB, 0, stream>>>(ws, out);
}

// Round 2
// 173.008 us; speedup vs baseline: 1.2785x; 1.2785x over previous
//
#include <hip/hip_runtime.h>
#include <math.h>

#define HWW 25600          // 160*160
#define CC 45
#define VV 724
#define VT 46              // v-tiles of 16 (736 padded)
#define SFS 784            // LDS row stride in bf16 elems (dword stride 392 == 8 mod 32)
#define PIX 16             // pixels per block
#define TPB 256
#define NBLK 3200          // 51200/16
#define CEPS2 1e-6f
#define NQ 9
#define WSSTRIDE 16
#define WS_RED_OFF 98304   // byte offset of reduction partials in ws (after 94208B Bpack)

typedef __attribute__((ext_vector_type(8))) short short8;
typedef __attribute__((ext_vector_type(4))) float f32x4;

__device__ __forceinline__ float charb_(float x){ return sqrtf(fmaf(x,x,CEPS2)); }

__device__ __forceinline__ unsigned short f2b(float x){
  unsigned u = __float_as_uint(x);
  unsigned r = (u + 0x7fffu + ((u>>16)&1u)) >> 16;
  return (unsigned short)r;
}
__device__ __forceinline__ float b2f(unsigned short h){
  return __uint_as_float(((unsigned)h)<<16);
}

__device__ __forceinline__ float red64_(float v){
  #pragma unroll
  for (int off=32; off; off>>=1) v += __shfl_xor(v, off, 64);
  return v;
}
__device__ __forceinline__ float red16_(float v){
  #pragma unroll
  for (int off=8; off; off>>=1) v += __shfl_xor(v, off, 64);
  return v;
}

__device__ __forceinline__ void top5_ins(float x, int ix, float v[5], int id[5]){
  if (x > v[4]) {
    v[4]=x; id[4]=ix;
    #pragma unroll
    for (int j=4; j>0; --j){
      if (v[j] > v[j-1]) {
        float tv=v[j]; v[j]=v[j-1]; v[j-1]=tv;
        int tq=id[j]; id[j]=id[j-1]; id[j-1]=tq;
      }
    }
  }
}

// ---- pack sf (45x724 f32) into MFMA B-fragment order, bf16, zero-padded to 64x736 ----
// Bpack[(vt*2+ks)*64 + lane][j] = bf16(sf[k][col]),  k = (lane>>4)*8 + j + 32*ks, col = vt*16 + (lane&15)
__global__ void pack_sf(const float* __restrict__ sf, unsigned short* __restrict__ bp)
{
  const int vt = blockIdx.x >> 1, ks = blockIdx.x & 1;
  const int lane = threadIdx.x;
  const int col = vt*16 + (lane & 15);
  unsigned short v[8];
  #pragma unroll
  for (int j=0;j<8;++j){
    int k = ((lane>>4)<<3) + j + (ks<<5);
    float x = (k < CC && col < VV) ? sf[k*VV + col] : 0.f;
    v[j] = f2b(x);
  }
  short8 pk;
  #pragma unroll
  for (int j=0;j<8;++j) pk[j] = (short)v[j];
  reinterpret_cast<short8*>(bp)[(blockIdx.x)*64 + lane] = pk;
}

__global__ __launch_bounds__(TPB, 2)
void fodf_main(const float* __restrict__ pred, const float* __restrict__ tgt,
               const float* __restrict__ sf, const float* __restrict__ mask,
               const unsigned short* __restrict__ bpack, float* __restrict__ ws)
{
  __shared__ float sPred[CC*PIX];
  __shared__ float sTgt[CC*PIX];
  __shared__ unsigned short sfP[PIX*SFS];
  __shared__ unsigned short sfT[PIX*SFS];
  __shared__ float sTopV[PIX][5];
  __shared__ int   sTopI[PIX][5];
  __shared__ float sMask[PIX];
  __shared__ float sRed[4][NQ];

  const int tid = threadIdx.x;
  const int pid0 = blockIdx.x * PIX;
  const int b = pid0 / HWW, hw0 = pid0 - b*HWW;

  // ---- stage channels (fp32) ----
  for (int i = tid; i < CC*PIX; i += TPB) {
    int c = i >> 4, p = i & 15;
    size_t off = (size_t)(b*CC + c)*HWW + hw0 + p;
    sPred[c*PIX + p] = pred[off];
    sTgt [c*PIX + p] = tgt[off];
  }
  if (tid < PIX) sMask[tid] = mask[pid0 + tid];
  __syncthreads();

  // ---- phase 1: MFMA GEMM -> sfP/sfT (bf16) ----
  {
    const int w = tid >> 6, lane = tid & 63;
    const int rt = w & 1;          // pixel half: rt*8 .. rt*8+7
    const int vh = w >> 1;         // vtile half
    const int lh = lane >> 4, row = lane & 15;
    // A-frag: rows 0-7 = pred pixels rt*8+row, rows 8-15 = tgt pixels rt*8+row-8
    const float* asrc = (row < 8) ? sPred : sTgt;
    const int pix8 = rt*8 + (row & 7);
    short8 af[2];
    #pragma unroll
    for (int ks=0; ks<2; ++ks){
      #pragma unroll
      for (int j=0;j<8;++j){
        int k = (lh<<3) + j + (ks<<5);
        float v = (k < CC) ? asrc[k*PIX + pix8] : 0.f;
        af[ks][j] = (short)f2b(v);
      }
    }
    const short8* Bp = reinterpret_cast<const short8*>(bpack);
    const int v0 = vh * 23, v1 = v0 + 23;
    // D row m = lh*4+r -> pred if m<8 else tgt; pixel = rt*8 + (m&7)
    unsigned short* dbase = ((lh < 2) ? sfP : sfT) + (rt*8 + ((lh & 1) << 2)) * SFS;
    short8 b0 = Bp[(v0*2+0)*64 + lane];
    short8 b1 = Bp[(v0*2+1)*64 + lane];
    for (int vt = v0; vt < v1; ++vt){
      short8 n0, n1;
      if (vt + 1 < v1){
        n0 = Bp[((vt+1)*2+0)*64 + lane];
        n1 = Bp[((vt+1)*2+1)*64 + lane];
      }
      f32x4 acc = {0.f,0.f,0.f,0.f};
      acc = __builtin_amdgcn_mfma_f32_16x16x32_bf16(af[0], b0, acc, 0, 0, 0);
      acc = __builtin_amdgcn_mfma_f32_16x16x32_bf16(af[1], b1, acc, 0, 0, 0);
      unsigned short* d = dbase + vt*16 + row;
      #pragma unroll
      for (int r=0;r<4;++r) d[r*SFS] = f2b(acc[r]);
      b0 = n0; b1 = n1;
    }
  }

  // ---- phase 2: per-pixel channel stats (fp32, independent of phase 1) ----
  float q_fodf=0, q_corr=0, q_power=0, q_mask=0;
  {
    const int p = tid >> 4, l16 = tid & 15;
    const float mp = sMask[p];
    float sp=0,st=0,spp=0,stt=0,spt=0,fod=0;
    float bp0=0,bp1=0,bp2=0,bp3=0,bp4=0;
    float bt0=0,bt1=0,bt2=0,bt3=0,bt4=0;
    #pragma unroll
    for (int cc3=0; cc3<3; ++cc3){
      int c = l16 + 16*cc3;
      if (c < CC) {
        float pv = sPred[c*PIX + p], tv = sTgt[c*PIX + p];
        float p2 = pv*pv, t2 = tv*tv;
        sp+=pv; st+=tv; spp+=p2; stt+=t2; spt+=pv*tv;
        fod += charb_(pv-tv);
        bp0 += (c<1)?p2:0.f;           bt0 += (c<1)?t2:0.f;
        bp1 += (c>=1&&c<6)?p2:0.f;     bt1 += (c>=1&&c<6)?t2:0.f;
        bp2 += (c>=6&&c<15)?p2:0.f;    bt2 += (c>=6&&c<15)?t2:0.f;
        bp3 += (c>=15&&c<28)?p2:0.f;   bt3 += (c>=15&&c<28)?t2:0.f;
        bp4 += (c>=28)?p2:0.f;         bt4 += (c>=28)?t2:0.f;
      }
    }
    sp=red16_(sp); st=red16_(st); spp=red16_(spp); stt=red16_(stt); spt=red16_(spt);
    fod=red16_(fod);
    bp0=red16_(bp0); bp1=red16_(bp1); bp2=red16_(bp2); bp3=red16_(bp3); bp4=red16_(bp4);
    bt0=red16_(bt0); bt1=red16_(bt1); bt2=red16_(bt2); bt3=red16_(bt3); bt4=red16_(bt4);
    if (l16 == 0) {
      const float n = (float)CC;
      float mpm = sp/n, mtm = st/n;
      float cov = spt - n*mpm*mtm;
      float vp = spp - n*mpm*mpm;
      float vt = stt - n*mtm*mtm;
      float denom = sqrtf(fmaxf(vp,0.f))*sqrtf(fmaxf(vt,0.f)) + 1e-6f;
      q_corr = (1.f - cov/denom)*mp;
      q_fodf = fod*mp;
      float pw = 0.f;
      pw += charb_(sqrtf(bp0+CEPS2) - sqrtf(bt0+CEPS2));
      pw += charb_(sqrtf(bp1+CEPS2) - sqrtf(bt1+CEPS2));
      pw += charb_(sqrtf(bp2+CEPS2) - sqrtf(bt2+CEPS2));
      pw += charb_(sqrtf(bp3+CEPS2) - sqrtf(bt3+CEPS2));
      pw += charb_(sqrtf(bp4+CEPS2) - sqrtf(bt4+CEPS2));
      q_power = pw*mp;
      q_mask = mp;
    }
  }
  __syncthreads();   // sfP/sfT complete

  // ---- phase 3: top-5 of relu(target_sf), 16 lanes per pixel ----
  {
    const int p = tid >> 4, l16 = tid & 15;
    float tv5[5]={-1.f,-1.f,-1.f,-1.f,-1.f};
    int   ti5[5]={0,0,0,0,0};
    const unsigned short* rowp = sfT + p*SFS;
    #pragma unroll 2
    for (int i=0;i<46;++i){
      int v = l16 + 16*i;
      if (v < VV){
        float x = fmaxf(b2f(rowp[v]), 0.f);
        top5_ins(x, v, tv5, ti5);
      }
    }
    #pragma unroll
    for (int off=8; off; off>>=1){
      float ov[5]; int oi[5];
      #pragma unroll
      for (int j=0;j<5;++j){ ov[j]=__shfl_xor(tv5[j],off,64); oi[j]=__shfl_xor(ti5[j],off,64); }
      #pragma unroll
      for (int j=0;j<5;++j) top5_ins(ov[j], oi[j], tv5, ti5);
    }
    if (l16 == 0){
      #pragma unroll
      for (int j=0;j<5;++j){ sTopV[p][j]=tv5[j]; sTopI[p][j]=ti5[j]; }
    }
  }
  __syncthreads();

  // ---- phase 4: sf_loss / nonneg / peak ----
  float q_sfn=0, q_sfd=0, q_nn=0, q_pk=0, q_cnt=0;
  #pragma unroll 1
  for (int p=0;p<PIX;++p){
    const float mp = sMask[p];
    const float invp = 1.f / fmaxf(sTopV[p][0], 1e-6f);
    const unsigned short* rp = sfP + p*SFS;
    const unsigned short* rt_ = sfT + p*SFS;
    for (int v = tid; v < VV; v += TPB){
      float ts = b2f(rt_[v]), ps = b2f(rp[v]);
      float pos = fmaxf(ts, 0.f);
      float tn = pos*invp;
      float wgt = fmaf(4.f*tn, tn, 1.f)*mp;
      q_sfn += charb_(ps - ts)*wgt;
      q_sfd += wgt;
      q_nn  += fmaxf(-ps, 0.f)*mp;
    }
  }
  if (tid < PIX*5) {
    int p = tid/5, k = tid - 5*p;
    float tv = sTopV[p][k];
    float thr = 0.25f * fmaxf(sTopV[p][0], 1e-6f);
    if (tv > thr && sMask[p] > 0.5f) {
      float pp = b2f(sfP[p*SFS + sTopI[p][k]]);
      q_pk = charb_(pp - tv);
      q_cnt = 1.f;
    }
  }

  // ---- block reduction -> per-block partials ----
  float q[NQ] = {q_fodf, q_corr, q_sfn, q_sfd, q_nn, q_pk, q_cnt, q_power, q_mask};
  #pragma unroll
  for (int i=0;i<NQ;++i) q[i] = red64_(q[i]);
  if ((tid & 63) == 0) {
    #pragma unroll
    for (int i=0;i<NQ;++i) sRed[tid>>6][i] = q[i];
  }
  __syncthreads();
  if (tid < NQ) {
    float s = sRed[0][tid]+sRed[1][tid]+sRed[2][tid]+sRed[3][tid];
    ws[blockIdx.x*WSSTRIDE + tid] = s;
  }
}

__global__ __launch_bounds__(TPB)
void fodf_final(const float* __restrict__ ws, float* __restrict__ out)
{
  const int tid = threadIdx.x;
  float s[NQ];
  #pragma unroll
  for (int i=0;i<NQ;++i) s[i]=0.f;
  for (int i = tid; i < NBLK; i += TPB) {
    #pragma unroll
    for (int qq=0;qq<NQ;++qq) s[qq] += ws[i*WSSTRIDE+qq];
  }
  #pragma unroll
  for (int i=0;i<NQ;++i) s[i] = red64_(s[i]);
  __shared__ float sw[4][NQ];
  if ((tid&63)==0){
    #pragma unroll
    for (int i=0;i<NQ;++i) sw[tid>>6][i]=s[i];
  }
  __syncthreads();
  if (tid==0){
    float t[NQ];
    #pragma unroll
    for (int i=0;i<NQ;++i) t[i]=sw[0][i]+sw[1][i]+sw[2][i]+sw[3][i];
    float msum = t[8];
    float fodf_loss = t[0]/fmaxf(msum*45.f,1.f);
    float corr_loss = t[1]/fmaxf(msum,1.f);
    float sf_loss   = t[2]/fmaxf(t[3],1.f);
    float nonneg    = t[4]/fmaxf(msum*724.f,1.f);
    float peak      = t[5]/fmaxf(t[6],1.f);
    float power     = t[7]/fmaxf(msum*5.f,1.f);
    out[0] = fodf_loss + 0.1f*corr_loss + sf_loss + 0.5f*peak + 0.1f*nonneg + 0.1f*power;
  }
}

extern "C" void kernel_launch(void* const* d_in, const int* in_sizes, int n_in,
                              void* d_out, int out_size, void* d_ws, size_t ws_size,
                              hipStream_t stream) {
  const float* pred = (const float*)d_in[0];
  const float* tgt  = (const float*)d_in[1];
  const float* sf   = (const float*)d_in[2];
  const float* mask = (const float*)d_in[3];
  unsigned short* bpack = (unsigned short*)d_ws;
  float* wsred = (float*)((char*)d_ws + WS_RED_OFF);
  float* out = (float*)d_out;
  pack_sf<<<VT*2, 64, 0, stream>>>(sf, bpack);
  fodf_main<<<NBLK, TPB, 0, stream>>>(pred, tgt, sf, mask, bpack, wsred);
  fodf_final<<<1, TPB, 0, stream>>>(wsred, out);
}